// Round 1
// baseline (730.434 us; speedup 1.0000x reference)
//
#include <hip/hip_runtime.h>

#define HID 64

// x[n][h] = emb[z[n]][h]
__global__ void embed_kernel(const int* __restrict__ z, const float* __restrict__ emb,
                             float* __restrict__ x, int n) {
    int t = blockIdx.x * blockDim.x + threadIdx.x;
    if (t >= n * HID) return;
    int node = t >> 6, h = t & 63;
    x[t] = emb[z[node] * HID + h];
}

// deg[row[e]]++
__global__ void hist_kernel(const int* __restrict__ row, int* __restrict__ deg, int e) {
    int t = blockIdx.x * blockDim.x + threadIdx.x;
    if (t < e) atomicAdd(&deg[row[t]], 1);
}

// single-block chunked exclusive scan: offs[0..n], offs[n] = total
__global__ void scan_kernel(const int* __restrict__ deg, int* __restrict__ offs, int n) {
    __shared__ int sm[1024];
    __shared__ int btot;
    int tid = threadIdx.x;
    int carry = 0;
    for (int base = 0; base < n; base += 1024) {
        int idx = base + tid;
        int v = (idx < n) ? deg[idx] : 0;
        sm[tid] = v;
        __syncthreads();
        for (int off = 1; off < 1024; off <<= 1) {
            int t2 = (tid >= off) ? sm[tid - off] : 0;
            __syncthreads();
            sm[tid] += t2;
            __syncthreads();
        }
        if (idx < n) offs[idx] = carry + sm[tid] - v;   // exclusive
        if (tid == 1023) btot = sm[1023];
        __syncthreads();
        carry += btot;
        __syncthreads();
    }
    if (tid == 0) offs[n] = carry;
}

// place edges into CSR slots; fuse rbf computation here (computed once, reused 3 layers)
__global__ void fill_kernel(const int* __restrict__ row, const int* __restrict__ col,
                            const float* __restrict__ pos, int* __restrict__ cursor,
                            int2* __restrict__ ecr, int e) {
    int t = blockIdx.x * blockDim.x + threadIdx.x;
    if (t >= e) return;
    int r = row[t], c = col[t];
    float dx = pos[3 * r]     - pos[3 * c];
    float dy = pos[3 * r + 1] - pos[3 * c + 1];
    float dz = pos[3 * r + 2] - pos[3 * c + 2];
    float rbf = expf(-sqrtf(dx * dx + dy * dy + dz * dz));
    int p = atomicAdd(&cursor[r], 1);
    ecr[p] = make_int2(c, __float_as_int(rbf));
}

// y[n] = x[n] + sum_{edges (n,c)} x[c] * rbf      (one wave per node, lane = h)
__global__ void gather_kernel(const float* __restrict__ x, const int* __restrict__ offs,
                              const int2* __restrict__ ecr, float* __restrict__ y, int n) {
    int h = threadIdx.x & 63;
    int wid = (blockIdx.x * blockDim.x + threadIdx.x) >> 6;
    int nw = (gridDim.x * blockDim.x) >> 6;
    for (int node = wid; node < n; node += nw) {
        int nu = __builtin_amdgcn_readfirstlane(node);   // wave-uniform
        int beg = offs[nu], end = offs[nu + 1];
        float acc = x[nu * HID + h];
        for (int i = beg; i < end; ++i) {
            int2 cr = ecr[i];                            // uniform -> scalar load
            acc = fmaf(x[cr.x * HID + h], __int_as_float(cr.y), acc);
        }
        y[nu * HID + h] = acc;
    }
}

// out[n][h] = relu(b[h] + sum_k y[n][k] * W[h][k])
// one wave per node; lane h keeps W row h in 64 VGPRs, reused across nodes.
// NOTE: intentionally NO __restrict__ on x/out — final layer runs in-place
// (safe: each wave reads+writes only its own row; store depends on all loads).
__global__ void linear_kernel(const float* x, const float* __restrict__ W,
                              const float* __restrict__ b, float* out, int n) {
    int h = threadIdx.x & 63;
    int wid = (blockIdx.x * blockDim.x + threadIdx.x) >> 6;
    int nw = (gridDim.x * blockDim.x) >> 6;
    float w[HID];
#pragma unroll
    for (int k = 0; k < HID; ++k) w[k] = W[h * HID + k];
    float bias = b[h];
    for (int node = wid; node < n; node += nw) {
        int nu = __builtin_amdgcn_readfirstlane(node);
        const float* xr = x + nu * HID;
        float acc = bias;
#pragma unroll
        for (int k = 0; k < HID; ++k) acc = fmaf(xr[k], w[k], acc);
        out[nu * HID + h] = fmaxf(acc, 0.0f);
    }
}

extern "C" void kernel_launch(void* const* d_in, const int* in_sizes, int n_in,
                              void* d_out, int out_size, void* d_ws, size_t ws_size,
                              hipStream_t stream) {
    const int*   z    = (const int*)d_in[0];
    const float* pos  = (const float*)d_in[1];
    const int*   eidx = (const int*)d_in[2];
    const float* emb  = (const float*)d_in[3];
    const float* Ws   = (const float*)d_in[4];
    const float* bs   = (const float*)d_in[5];
    int n = in_sizes[0];
    int e = in_sizes[2] / 2;
    int nlayers = in_sizes[4] / (HID * HID);
    const int* row = eidx;
    const int* col = eidx + e;
    float* out = (float*)d_out;

    char* ws = (char*)d_ws;
    float* A      = (float*)ws;                               // n*64 floats (25.6 MB)
    int2*  ecr    = (int2*)(ws + (size_t)n * HID * 4);        // e int2 (8 MB)
    int*   deg    = (int*)((char*)ecr + (size_t)e * 8);
    int*   offs   = deg + (n + 1);
    int*   cursor = offs + (n + 1);

    hipMemsetAsync(deg, 0, (n + 1) * sizeof(int), stream);
    embed_kernel<<<(n * HID + 255) / 256, 256, 0, stream>>>(z, emb, A, n);
    hist_kernel<<<(e + 255) / 256, 256, 0, stream>>>(row, deg, e);
    scan_kernel<<<1, 1024, 0, stream>>>(deg, offs, n);
    hipMemcpyAsync(cursor, offs, n * sizeof(int), hipMemcpyDeviceToDevice, stream);
    fill_kernel<<<(e + 255) / 256, 256, 0, stream>>>(row, col, pos, cursor, ecr, e);

    for (int l = 0; l < nlayers; ++l) {
        // gather: A -> out (residual + aggregation)
        gather_kernel<<<2048, 256, 0, stream>>>(A, offs, ecr, out, n);
        // linear: out -> A (layers 0..L-2), out -> out in-place (final layer)
        float* dst = (l == nlayers - 1) ? out : A;
        linear_kernel<<<1024, 256, 0, stream>>>(out, Ws + (size_t)l * HID * HID,
                                                bs + (size_t)l * HID, dst, n);
    }
}

// Round 2
// 573.682 us; speedup vs baseline: 1.2732x; 1.2732x over previous
//
#include <hip/hip_runtime.h>

#define HID 64
#define SCAN_BLOCK 256
#define SCAN_ITEMS 16
#define SCAN_TILE (SCAN_BLOCK * SCAN_ITEMS)   // 4096 elements per block

// x[n][h] = emb[z[n]][h]
__global__ void embed_kernel(const int* __restrict__ z, const float* __restrict__ emb,
                             float* __restrict__ x, int n) {
    int t = blockIdx.x * blockDim.x + threadIdx.x;
    if (t >= n * HID) return;
    int node = t >> 6, h = t & 63;
    x[t] = emb[z[node] * HID + h];
}

// deg[row[e]]++
__global__ void hist_kernel(const int* __restrict__ row, int* __restrict__ deg, int e) {
    int t = blockIdx.x * blockDim.x + threadIdx.x;
    if (t < e) atomicAdd(&deg[row[t]], 1);
}

// ---- 3-phase exclusive scan of deg[0..n1) into offs[0..n1) ----
// Phase A: per-block local exclusive scan + block totals.
__global__ void scanA_kernel(const int* __restrict__ deg, int* __restrict__ offs,
                             int* __restrict__ bsums, int n1) {
    __shared__ int wsum[SCAN_BLOCK / 64];
    int tid  = threadIdx.x;
    int lane = tid & 63, w = tid >> 6;
    int tbase = blockIdx.x * SCAN_TILE + tid * SCAN_ITEMS;

    int vals[SCAN_ITEMS];
    int s = 0;
#pragma unroll
    for (int i = 0; i < SCAN_ITEMS; ++i) {
        int idx = tbase + i;
        vals[i] = (idx < n1) ? deg[idx] : 0;
        s += vals[i];
    }
    // inclusive wave scan of per-thread sums
    int sc = s;
#pragma unroll
    for (int d = 1; d < 64; d <<= 1) {
        int t2 = __shfl_up(sc, d);
        if (lane >= d) sc += t2;
    }
    if (lane == 63) wsum[w] = sc;
    __syncthreads();
    int woff = 0;
    for (int i = 0; i < w; ++i) woff += wsum[i];
    int texcl = woff + sc - s;                 // exclusive prefix of this thread
    if (tid == 0) {
        int tot = 0;
        for (int i = 0; i < SCAN_BLOCK / 64; ++i) tot += wsum[i];
        bsums[blockIdx.x] = tot;
    }
    int run = 0;
#pragma unroll
    for (int i = 0; i < SCAN_ITEMS; ++i) {
        int idx = tbase + i;
        if (idx < n1) offs[idx] = texcl + run;
        run += vals[i];
    }
}

// Phase B: exclusive scan of block sums (nb small, chunked single block).
__global__ void scanB_kernel(int* __restrict__ bsums, int nb) {
    __shared__ int wsum[SCAN_BLOCK / 64];
    __shared__ int chunk_tot;
    int tid = threadIdx.x, lane = tid & 63, w = tid >> 6;
    int carry = 0;
    for (int base = 0; base < nb; base += SCAN_BLOCK) {
        int idx = base + tid;
        int v = (idx < nb) ? bsums[idx] : 0;
        int sc = v;
#pragma unroll
        for (int d = 1; d < 64; d <<= 1) {
            int t2 = __shfl_up(sc, d);
            if (lane >= d) sc += t2;
        }
        if (lane == 63) wsum[w] = sc;
        __syncthreads();
        int woff = 0;
        for (int i = 0; i < w; ++i) woff += wsum[i];
        if (idx < nb) bsums[idx] = carry + woff + sc - v;   // exclusive
        if (tid == SCAN_BLOCK - 1) chunk_tot = woff + sc;
        __syncthreads();
        carry += chunk_tot;
        __syncthreads();
    }
}

// Phase C: add scanned block offsets. (256 | 4096 so tile idx is block-uniform.)
__global__ void scanC_kernel(int* __restrict__ offs, const int* __restrict__ bsums, int n1) {
    int t = blockIdx.x * blockDim.x + threadIdx.x;
    if (t < n1) offs[t] += bsums[t / SCAN_TILE];
}

// place edges into CSR slots; fuse rbf computation (computed once, reused 3 layers)
__global__ void fill_kernel(const int* __restrict__ row, const int* __restrict__ col,
                            const float* __restrict__ pos, int* __restrict__ cursor,
                            int2* __restrict__ ecr, int e) {
    int t = blockIdx.x * blockDim.x + threadIdx.x;
    if (t >= e) return;
    int r = row[t], c = col[t];
    float dx = pos[3 * r]     - pos[3 * c];
    float dy = pos[3 * r + 1] - pos[3 * c + 1];
    float dz = pos[3 * r + 2] - pos[3 * c + 2];
    float rbf = expf(-sqrtf(dx * dx + dy * dy + dz * dz));
    int p = atomicAdd(&cursor[r], 1);
    ecr[p] = make_int2(c, __float_as_int(rbf));
}

// y[n] = x[n] + sum_{edges (n,c)} x[c] * rbf      (one wave per node, lane = h)
__global__ void gather_kernel(const float* __restrict__ x, const int* __restrict__ offs,
                              const int2* __restrict__ ecr, float* __restrict__ y, int n) {
    int h = threadIdx.x & 63;
    int wid = (blockIdx.x * blockDim.x + threadIdx.x) >> 6;
    int nw = (gridDim.x * blockDim.x) >> 6;
    for (int node = wid; node < n; node += nw) {
        int nu = __builtin_amdgcn_readfirstlane(node);   // wave-uniform
        int beg = offs[nu], end = offs[nu + 1];
        float acc = x[nu * HID + h];
        for (int i = beg; i < end; ++i) {
            int2 cr = ecr[i];                            // uniform -> scalar load
            acc = fmaf(x[cr.x * HID + h], __int_as_float(cr.y), acc);
        }
        y[nu * HID + h] = acc;
    }
}

// out[n][h] = relu(b[h] + sum_k y[n][k] * W[h][k])
// one wave per node; lane h keeps W row h in 64 VGPRs, reused across nodes.
// NOTE: intentionally NO __restrict__ on x/out — final layer runs in-place
// (safe: each wave reads+writes only its own row; store depends on all loads).
__global__ void linear_kernel(const float* x, const float* __restrict__ W,
                              const float* __restrict__ b, float* out, int n) {
    int h = threadIdx.x & 63;
    int wid = (blockIdx.x * blockDim.x + threadIdx.x) >> 6;
    int nw = (gridDim.x * blockDim.x) >> 6;
    float w[HID];
#pragma unroll
    for (int k = 0; k < HID; ++k) w[k] = W[h * HID + k];
    float bias = b[h];
    for (int node = wid; node < n; node += nw) {
        int nu = __builtin_amdgcn_readfirstlane(node);
        const float* xr = x + nu * HID;
        float acc = bias;
#pragma unroll
        for (int k = 0; k < HID; ++k) acc = fmaf(xr[k], w[k], acc);
        out[nu * HID + h] = fmaxf(acc, 0.0f);
    }
}

extern "C" void kernel_launch(void* const* d_in, const int* in_sizes, int n_in,
                              void* d_out, int out_size, void* d_ws, size_t ws_size,
                              hipStream_t stream) {
    const int*   z    = (const int*)d_in[0];
    const float* pos  = (const float*)d_in[1];
    const int*   eidx = (const int*)d_in[2];
    const float* emb  = (const float*)d_in[3];
    const float* Ws   = (const float*)d_in[4];
    const float* bs   = (const float*)d_in[5];
    int n = in_sizes[0];
    int e = in_sizes[2] / 2;
    int nlayers = in_sizes[4] / (HID * HID);
    const int* row = eidx;
    const int* col = eidx + e;
    float* out = (float*)d_out;

    char* ws = (char*)d_ws;
    float* A      = (float*)ws;                               // n*64 floats (25.6 MB)
    int2*  ecr    = (int2*)(ws + (size_t)n * HID * 4);        // e int2 (8 MB)
    int*   deg    = (int*)((char*)ecr + (size_t)e * 8);
    int*   offs   = deg + (n + 1);
    int*   cursor = offs + (n + 1);
    int*   bsums  = cursor + (n + 1);

    int n1 = n + 1;
    int nb = (n1 + SCAN_TILE - 1) / SCAN_TILE;

    hipMemsetAsync(deg, 0, n1 * sizeof(int), stream);
    embed_kernel<<<(n * HID + 255) / 256, 256, 0, stream>>>(z, emb, A, n);
    hist_kernel<<<(e + 255) / 256, 256, 0, stream>>>(row, deg, e);
    scanA_kernel<<<nb, SCAN_BLOCK, 0, stream>>>(deg, offs, bsums, n1);
    scanB_kernel<<<1, SCAN_BLOCK, 0, stream>>>(bsums, nb);
    scanC_kernel<<<(n1 + 255) / 256, 256, 0, stream>>>(offs, bsums, n1);
    hipMemcpyAsync(cursor, offs, n * sizeof(int), hipMemcpyDeviceToDevice, stream);
    fill_kernel<<<(e + 255) / 256, 256, 0, stream>>>(row, col, pos, cursor, ecr, e);

    for (int l = 0; l < nlayers; ++l) {
        // gather: A -> out (residual + aggregation)
        gather_kernel<<<2048, 256, 0, stream>>>(A, offs, ecr, out, n);
        // linear: out -> A (layers 0..L-2), out -> out in-place (final layer)
        float* dst = (l == nlayers - 1) ? out : A;
        linear_kernel<<<1024, 256, 0, stream>>>(out, Ws + (size_t)l * HID * HID,
                                                bs + (size_t)l * HID, dst, n);
    }
}

// Round 3
// 432.429 us; speedup vs baseline: 1.6891x; 1.3267x over previous
//
#include <hip/hip_runtime.h>

#define HID 64
#define SCAN_BLOCK 256
#define SCAN_ITEMS 16
#define SCAN_TILE (SCAN_BLOCK * SCAN_ITEMS)   // 4096 elements per block

// x[n][h] = emb[z[n]][h]
__global__ void embed_kernel(const int* __restrict__ z, const float* __restrict__ emb,
                             float* __restrict__ x, int n) {
    int t = blockIdx.x * blockDim.x + threadIdx.x;
    if (t >= n * HID) return;
    int node = t >> 6, h = t & 63;
    x[t] = emb[z[node] * HID + h];
}

// deg[row[e]]++
__global__ void hist_kernel(const int* __restrict__ row, int* __restrict__ deg, int e) {
    int t = blockIdx.x * blockDim.x + threadIdx.x;
    if (t < e) atomicAdd(&deg[row[t]], 1);
}

// ---- 3-phase exclusive scan of deg[0..n1) into offs[0..n1) ----
__global__ void scanA_kernel(const int* __restrict__ deg, int* __restrict__ offs,
                             int* __restrict__ bsums, int n1) {
    __shared__ int wsum[SCAN_BLOCK / 64];
    int tid  = threadIdx.x;
    int lane = tid & 63, w = tid >> 6;
    int tbase = blockIdx.x * SCAN_TILE + tid * SCAN_ITEMS;

    int vals[SCAN_ITEMS];
    int s = 0;
#pragma unroll
    for (int i = 0; i < SCAN_ITEMS; ++i) {
        int idx = tbase + i;
        vals[i] = (idx < n1) ? deg[idx] : 0;
        s += vals[i];
    }
    int sc = s;
#pragma unroll
    for (int d = 1; d < 64; d <<= 1) {
        int t2 = __shfl_up(sc, d);
        if (lane >= d) sc += t2;
    }
    if (lane == 63) wsum[w] = sc;
    __syncthreads();
    int woff = 0;
    for (int i = 0; i < w; ++i) woff += wsum[i];
    int texcl = woff + sc - s;
    if (tid == 0) {
        int tot = 0;
        for (int i = 0; i < SCAN_BLOCK / 64; ++i) tot += wsum[i];
        bsums[blockIdx.x] = tot;
    }
    int run = 0;
#pragma unroll
    for (int i = 0; i < SCAN_ITEMS; ++i) {
        int idx = tbase + i;
        if (idx < n1) offs[idx] = texcl + run;
        run += vals[i];
    }
}

__global__ void scanB_kernel(int* __restrict__ bsums, int nb) {
    __shared__ int wsum[SCAN_BLOCK / 64];
    __shared__ int chunk_tot;
    int tid = threadIdx.x, lane = tid & 63, w = tid >> 6;
    int carry = 0;
    for (int base = 0; base < nb; base += SCAN_BLOCK) {
        int idx = base + tid;
        int v = (idx < nb) ? bsums[idx] : 0;
        int sc = v;
#pragma unroll
        for (int d = 1; d < 64; d <<= 1) {
            int t2 = __shfl_up(sc, d);
            if (lane >= d) sc += t2;
        }
        if (lane == 63) wsum[w] = sc;
        __syncthreads();
        int woff = 0;
        for (int i = 0; i < w; ++i) woff += wsum[i];
        if (idx < nb) bsums[idx] = carry + woff + sc - v;
        if (tid == SCAN_BLOCK - 1) chunk_tot = woff + sc;
        __syncthreads();
        carry += chunk_tot;
        __syncthreads();
    }
}

__global__ void scanC_kernel(int* __restrict__ offs, const int* __restrict__ bsums, int n1) {
    int t = blockIdx.x * blockDim.x + threadIdx.x;
    if (t < n1) offs[t] += bsums[t / SCAN_TILE];
}

// place edges into CSR slots; fuse rbf computation (computed once, reused 3 layers)
__global__ void fill_kernel(const int* __restrict__ row, const int* __restrict__ col,
                            const float* __restrict__ pos, int* __restrict__ cursor,
                            int2* __restrict__ ecr, int e) {
    int t = blockIdx.x * blockDim.x + threadIdx.x;
    if (t >= e) return;
    int r = row[t], c = col[t];
    float dx = pos[3 * r]     - pos[3 * c];
    float dy = pos[3 * r + 1] - pos[3 * c + 1];
    float dz = pos[3 * r + 2] - pos[3 * c + 2];
    float rbf = expf(-sqrtf(dx * dx + dy * dy + dz * dz));
    int p = atomicAdd(&cursor[r], 1);
    ecr[p] = make_int2(c, __float_as_int(rbf));
}

// y[n] = x[n] + sum_{edges (n,c)} x[c] * rbf
// One wave per node, lane = h. Edge records are loaded 64-at-a-time with ONE
// coalesced vector load (lane = edge slot), broadcast via __shfl; all row-load
// addresses are then register-resident -> 8 independent 256B row loads in
// flight per wave (latency hiding), vs 1 with the chained uniform-load loop.
__global__ void gather_kernel(const float* __restrict__ x, const int* __restrict__ offs,
                              const int2* __restrict__ ecr, float* __restrict__ y, int n) {
    int lane = threadIdx.x & 63;
    int wid = (blockIdx.x * blockDim.x + threadIdx.x) >> 6;
    int nw = (gridDim.x * blockDim.x) >> 6;
    for (int node = wid; node < n; node += nw) {
        int nu = __builtin_amdgcn_readfirstlane(node);
        int beg = offs[nu], end = offs[nu + 1];
        float acc = x[nu * HID + lane];
        for (int cbeg = beg; cbeg < end; cbeg += 64) {
            int m = end - cbeg; if (m > 64) m = 64;
            int2 cr = (lane < m) ? ecr[cbeg + lane] : make_int2(0, 0);
            int cc = cr.x;
            float rr = __int_as_float(cr.y);
            int j = 0;
            for (; j + 8 <= m; j += 8) {
                int   c0 = __shfl(cc, j);     float r0 = __shfl(rr, j);
                int   c1 = __shfl(cc, j + 1); float r1 = __shfl(rr, j + 1);
                int   c2 = __shfl(cc, j + 2); float r2 = __shfl(rr, j + 2);
                int   c3 = __shfl(cc, j + 3); float r3 = __shfl(rr, j + 3);
                int   c4 = __shfl(cc, j + 4); float r4 = __shfl(rr, j + 4);
                int   c5 = __shfl(cc, j + 5); float r5 = __shfl(rr, j + 5);
                int   c6 = __shfl(cc, j + 6); float r6 = __shfl(rr, j + 6);
                int   c7 = __shfl(cc, j + 7); float r7 = __shfl(rr, j + 7);
                float x0 = x[c0 * HID + lane];
                float x1 = x[c1 * HID + lane];
                float x2 = x[c2 * HID + lane];
                float x3 = x[c3 * HID + lane];
                float x4 = x[c4 * HID + lane];
                float x5 = x[c5 * HID + lane];
                float x6 = x[c6 * HID + lane];
                float x7 = x[c7 * HID + lane];
                acc = fmaf(x0, r0, acc);
                acc = fmaf(x1, r1, acc);
                acc = fmaf(x2, r2, acc);
                acc = fmaf(x3, r3, acc);
                acc = fmaf(x4, r4, acc);
                acc = fmaf(x5, r5, acc);
                acc = fmaf(x6, r6, acc);
                acc = fmaf(x7, r7, acc);
            }
            for (; j < m; ++j) {
                int   c0 = __shfl(cc, j);
                float r0 = __shfl(rr, j);
                acc = fmaf(x[c0 * HID + lane], r0, acc);
            }
        }
        y[nu * HID + lane] = acc;
    }
}

// out[n][h] = relu(b[h] + sum_k y[n][k] * W[h][k])
// one wave per node; lane h keeps W row h in 64 VGPRs, reused across nodes.
// __restrict__ is safe even for the in-place final layer: each wave reads and
// writes ONLY its own disjoint node row, so no cross-wave or cross-iteration
// aliasing actually occurs; restrict lets the compiler pipeline across nodes.
__global__ void linear_kernel(const float* __restrict__ x, const float* __restrict__ W,
                              const float* __restrict__ b, float* __restrict__ out, int n) {
    int h = threadIdx.x & 63;
    int wid = (blockIdx.x * blockDim.x + threadIdx.x) >> 6;
    int nw = (gridDim.x * blockDim.x) >> 6;
    float w[HID];
#pragma unroll
    for (int k = 0; k < HID; ++k) w[k] = W[h * HID + k];
    float bias = b[h];
    for (int node = wid; node < n; node += nw) {
        int nu = __builtin_amdgcn_readfirstlane(node);
        const float* xr = x + nu * HID;
        float acc = bias;
#pragma unroll
        for (int k = 0; k < HID; ++k) acc = fmaf(xr[k], w[k], acc);
        out[nu * HID + h] = fmaxf(acc, 0.0f);
    }
}

extern "C" void kernel_launch(void* const* d_in, const int* in_sizes, int n_in,
                              void* d_out, int out_size, void* d_ws, size_t ws_size,
                              hipStream_t stream) {
    const int*   z    = (const int*)d_in[0];
    const float* pos  = (const float*)d_in[1];
    const int*   eidx = (const int*)d_in[2];
    const float* emb  = (const float*)d_in[3];
    const float* Ws   = (const float*)d_in[4];
    const float* bs   = (const float*)d_in[5];
    int n = in_sizes[0];
    int e = in_sizes[2] / 2;
    int nlayers = in_sizes[4] / (HID * HID);
    const int* row = eidx;
    const int* col = eidx + e;
    float* out = (float*)d_out;

    char* ws = (char*)d_ws;
    float* A      = (float*)ws;                               // n*64 floats (25.6 MB)
    int2*  ecr    = (int2*)(ws + (size_t)n * HID * 4);        // e int2 (8 MB)
    int*   deg    = (int*)((char*)ecr + (size_t)e * 8);
    int*   offs   = deg + (n + 1);
    int*   cursor = offs + (n + 1);
    int*   bsums  = cursor + (n + 1);

    int n1 = n + 1;
    int nb = (n1 + SCAN_TILE - 1) / SCAN_TILE;

    hipMemsetAsync(deg, 0, n1 * sizeof(int), stream);
    embed_kernel<<<(n * HID + 255) / 256, 256, 0, stream>>>(z, emb, A, n);
    hist_kernel<<<(e + 255) / 256, 256, 0, stream>>>(row, deg, e);
    scanA_kernel<<<nb, SCAN_BLOCK, 0, stream>>>(deg, offs, bsums, n1);
    scanB_kernel<<<1, SCAN_BLOCK, 0, stream>>>(bsums, nb);
    scanC_kernel<<<(n1 + 255) / 256, 256, 0, stream>>>(offs, bsums, n1);
    hipMemcpyAsync(cursor, offs, n * sizeof(int), hipMemcpyDeviceToDevice, stream);
    fill_kernel<<<(e + 255) / 256, 256, 0, stream>>>(row, col, pos, cursor, ecr, e);

    for (int l = 0; l < nlayers; ++l) {
        gather_kernel<<<2048, 256, 0, stream>>>(A, offs, ecr, out, n);
        float* dst = (l == nlayers - 1) ? out : A;
        linear_kernel<<<1024, 256, 0, stream>>>(out, Ws + (size_t)l * HID * HID,
                                                bs + (size_t)l * HID, dst, n);
    }
}